// Round 10
// baseline (366.659 us; speedup 1.0000x reference)
//
#include <hip/hip_runtime.h>

#define BATCH 16384
#define RT    16        // batch rows per block -> 1024 blocks -> 4 blocks/CU

typedef unsigned short u16;
typedef __attribute__((ext_vector_type(8))) short short8;
typedef __attribute__((ext_vector_type(8))) _Float16 f16x8;
typedef __attribute__((ext_vector_type(4))) float f32x4;

// ---------- fp16 helpers (storage = u16 bit patterns) ----------
__device__ __forceinline__ u16 f2h(float x) {
    union { _Float16 h; u16 u; } c; c.h = (_Float16)x; return c.u;
}
__device__ __forceinline__ float h2f(u16 b) {
    union { u16 u; _Float16 h; } c; c.u = b; return (float)c.h;
}
__device__ __forceinline__ unsigned int pk2(float a, float b) {
    union { __attribute__((ext_vector_type(2))) __fp16 v; unsigned int u; } c;
    c.v = __builtin_amdgcn_cvt_pkrtz(a, b);
    return c.u;
}
// 16-lane sum via DPP (verified in R9: pure VALU, correct, no DS pipe)
__device__ __forceinline__ float red16(float x) {
    x += __builtin_bit_cast(float, __builtin_amdgcn_update_dpp(
             0, __builtin_bit_cast(int, x), 0xB1, 0xF, 0xF, true));
    x += __builtin_bit_cast(float, __builtin_amdgcn_update_dpp(
             0, __builtin_bit_cast(int, x), 0x4E, 0xF, 0xF, true));
    x += __builtin_bit_cast(float, __builtin_amdgcn_update_dpp(
             0, __builtin_bit_cast(int, x), 0x124, 0xF, 0xF, true));
    x += __builtin_bit_cast(float, __builtin_amdgcn_update_dpp(
             0, __builtin_bit_cast(int, x), 0x128, 0xF, 0xF, true));
    return x;
}

// ================= weight pre-pack kernels (single fp16) =================
__global__ void prep_w1(const float* __restrict__ W1, const int* __restrict__ G,
                        u16* __restrict__ P) {
    int idx = blockIdx.x * 256 + threadIdx.x;   // 64*64*256 exactly
    int n = idx & 255;
    int k = (idx >> 8) & 63;
    int v = idx >> 14;
    float w = (G[k * 64 + v] > 0) ? W1[((size_t)v * 65 + k) * 256 + n] : 0.0f;
    P[(((size_t)(v * 8 + (k >> 3)) * 256 + n) << 3) + (k & 7)] = f2h(w);
}
__global__ void prep_w2(const float* __restrict__ W2, u16* __restrict__ P) {
    int idx = blockIdx.x * 256 + threadIdx.x;   // 64*256*128 exactly
    int n = idx & 127;
    int k = (idx >> 7) & 255;
    int v = idx >> 15;
    P[(((size_t)(v * 32 + (k >> 3)) * 128 + n) << 3) + (k & 7)] =
        f2h(W2[((size_t)v * 256 + k) * 128 + n]);
}

// ================= persistent fused kernel =================
#define AST   72     // Y-tile stride (u16): 144B = 16 mod 128
#define H1ST  264    // h1 stride (u16): 528B = 16 mod 128

__global__ __launch_bounds__(512, 8)
void sen_fused(const float* __restrict__ U,
               const u16* __restrict__ P1, const u16* __restrict__ P2,
               const float* __restrict__ W1, const float* __restrict__ b1,
               const float* __restrict__ b2, const float* __restrict__ W3,
               const float* __restrict__ b3, float* __restrict__ Y)
{
    __shared__ __attribute__((aligned(16))) u16 Ah[RT * AST];
    __shared__ __attribute__((aligned(16))) u16 Al[RT * AST];
    __shared__ __attribute__((aligned(16))) u16 h1[RT * H1ST];
    __shared__ float yp[8][RT];

    const int tid  = threadIdx.x;
    const int row0 = blockIdx.x * RT;

    // zero Y tile incl. pad (stale LDS bits could be NaN; NaN*0 = NaN in MFMA)
    {
        short8 z = {0,0,0,0,0,0,0,0};
        for (int i = tid; i < (RT * AST) / 8; i += 512) {
            *(short8*)&Ah[i * 8] = z;
            *(short8*)&Al[i * 8] = z;
        }
    }
    __syncthreads();

    const int w  = tid >> 6, l = tid & 63;
    const int lr = l & 15,  lk = l >> 4;
    const int mg = w;   // phase 1: dim group (32 dims, W1 read once/block)
    const int cg = w;   // phase 2: col group (16 cols, W2 read once/block)

    #pragma unroll 1
    for (int v = 0; v < 64; ++v) {
        // ---- per-step parameter loads (latency hides under MFMAs) ----
        f32x4 b1v[2], w64v[2];
        #pragma unroll
        for (int ni = 0; ni < 2; ++ni) {
            const int dim = mg * 32 + ni * 16 + lk * 4;
            b1v[ni]  = *(const f32x4*)(b1 + v * 256 + dim);
            w64v[ni] = *(const f32x4*)(W1 + ((size_t)v * 65 + 64) * 256 + dim);
        }
        const float u_c = U[(size_t)(row0 + lr) * 64 + v];
        const float b2c = b2[v * 128 + cg * 16 + lr];
        const float w3c = W3[v * 128 + cg * 16 + lr];

        // ======== Phase 1 — Layer 1 (operand-swapped): h1t[dim][brow] ========
        // wave: dims mg*32..+31 (ni=2) x 16 brows, K=64
        f32x4 acc1[2];
        acc1[0] = (f32x4){0.f, 0.f, 0.f, 0.f};
        acc1[1] = acc1[0];

        #pragma unroll
        for (int kt = 0; kt < 2; ++kt) {
            const int o = lr * AST + kt * 32 + lk * 8;
            const f16x8 Yfh = *(const f16x8*)&Ah[o];
            const f16x8 Yfl = *(const f16x8*)&Al[o];
            #pragma unroll
            for (int ni = 0; ni < 2; ++ni) {
                const f16x8 Wf = *(const f16x8*)&P1[
                    (((size_t)(v * 8 + kt * 4 + lk) * 256) + mg * 32 + ni * 16 + lr) << 3];
                acc1[ni] = __builtin_amdgcn_mfma_f32_16x16x32_f16(Wf, Yfh, acc1[ni], 0, 0, 0);
                acc1[ni] = __builtin_amdgcn_mfma_f32_16x16x32_f16(Wf, Yfl, acc1[ni], 0, 0, 0);
            }
        }
        // epilogue: + bias + u * W1[64,:] (exact fp32), relu, fp16 pack, store
        #pragma unroll
        for (int ni = 0; ni < 2; ++ni) {
            float x[4];
            #pragma unroll
            for (int r = 0; r < 4; ++r)
                x[r] = fmaxf(acc1[ni][r] + b1v[ni][r] + u_c * w64v[ni][r], 0.0f);
            unsigned long long pk = (unsigned long long)pk2(x[0], x[1])
                                  | ((unsigned long long)pk2(x[2], x[3]) << 32);
            *(unsigned long long*)&h1[lr * H1ST + mg * 32 + ni * 16 + lk * 4] = pk;
        }
        __syncthreads();   // B1: h1 written -> phase 2 may read

        // ======== Phase 2 — Layer 2 (bias via acc init) + in-reg layer 3 ========
        f32x4 acc2 = (f32x4){b2c, b2c, b2c, b2c};
        #pragma unroll
        for (int kt = 0; kt < 8; ++kt) {
            const f16x8 Hf = *(const f16x8*)&h1[lr * H1ST + kt * 32 + lk * 8];
            const f16x8 Bf = *(const f16x8*)&P2[
                (((size_t)(v * 32 + kt * 4 + lk) * 128) + cg * 16 + lr) << 3];
            acc2 = __builtin_amdgcn_mfma_f32_16x16x32_f16(Hf, Bf, acc2, 0, 0, 0);
        }
        // layer-3 partials: relu * w3, DPP-reduce over the 16 lr lanes (cols)
        f32x4 sv;
        #pragma unroll
        for (int r = 0; r < 4; ++r)
            sv[r] = red16(fmaxf(acc2[r], 0.0f) * w3c);
        if (lr == 0)
            *(f32x4*)&yp[cg][lk * 4] = sv;
        __syncthreads();   // B2: yp visible; all h1 reads done

        // ======== Phase 3 — finalize y column into the Y tile ========
        if (tid < RT) {
            float y = b3[v];
            #pragma unroll
            for (int c = 0; c < 8; ++c) y += yp[c][tid];
            u16 h = f2h(y);
            Ah[tid * AST + v] = h;
            Al[tid * AST + v] = f2h(y - h2f(h));
        }
        __syncthreads();   // B3: Y col v visible; h1 free for next step
    }

    // ---- final coalesced store (hi+lo reconstruct) ----
    if (tid < RT * 16) {
        const int row = tid >> 4, c4 = (tid & 15) * 4;
        const u16* hv = &Ah[row * AST + c4];
        const u16* lv = &Al[row * AST + c4];
        float4 o;
        o.x = h2f(hv[0]) + h2f(lv[0]);
        o.y = h2f(hv[1]) + h2f(lv[1]);
        o.z = h2f(hv[2]) + h2f(lv[2]);
        o.w = h2f(hv[3]) + h2f(lv[3]);
        *(float4*)(Y + (size_t)(row0 + row) * 64 + c4) = o;
    }
}

extern "C" void kernel_launch(void* const* d_in, const int* in_sizes, int n_in,
                              void* d_out, int out_size, void* d_ws, size_t ws_size,
                              hipStream_t stream) {
    // inputs: X, U, causal_graph, W1, b1, W2, b2, W3, b3  (X never feeds the recursion)
    const float* U  = (const float*)d_in[1];
    const int*   G  = (const int*)  d_in[2];
    const float* W1 = (const float*)d_in[3];
    const float* b1 = (const float*)d_in[4];
    const float* W2 = (const float*)d_in[5];
    const float* b2 = (const float*)d_in[6];
    const float* W3 = (const float*)d_in[7];
    const float* b3 = (const float*)d_in[8];
    float* Y = (float*)d_out;

    const size_t S1 = (size_t)64 * 64 * 256;     // u16 elements, packed W1
    u16* P1 = (u16*)d_ws;
    u16* P2 = P1 + S1;

    prep_w1<<<(64 * 64 * 256) / 256, 256, 0, stream>>>(W1, G, P1);
    prep_w2<<<(64 * 256 * 128) / 256, 256, 0, stream>>>(W2, P2);
    sen_fused<<<BATCH / RT, 512, 0, stream>>>(U, P1, P2, W1, b1, b2, W3, b3, Y);
}

// Round 11
// 317.955 us; speedup vs baseline: 1.1532x; 1.1532x over previous
//
#include <hip/hip_runtime.h>

#define BATCH 16384
#define RT    64        // batch rows per block -> 256 blocks -> 1 block/CU

typedef unsigned short u16;
typedef __attribute__((ext_vector_type(8))) short short8;
typedef __attribute__((ext_vector_type(8))) _Float16 f16x8;
typedef __attribute__((ext_vector_type(4))) float f32x4;

// ---------- fp16 helpers (storage = u16 bit patterns) ----------
__device__ __forceinline__ u16 f2h(float x) {
    union { _Float16 h; u16 u; } c; c.h = (_Float16)x; return c.u;
}
__device__ __forceinline__ float h2f(u16 b) {
    union { u16 u; _Float16 h; } c; c.u = b; return (float)c.h;
}
__device__ __forceinline__ unsigned int pk2(float a, float b) {
    union { __attribute__((ext_vector_type(2))) __fp16 v; unsigned int u; } c;
    c.v = __builtin_amdgcn_cvt_pkrtz(a, b);
    return c.u;
}
// 16-lane sum via DPP (verified R9/R10: pure VALU, no DS pipe)
__device__ __forceinline__ float red16(float x) {
    x += __builtin_bit_cast(float, __builtin_amdgcn_update_dpp(
             0, __builtin_bit_cast(int, x), 0xB1, 0xF, 0xF, true));
    x += __builtin_bit_cast(float, __builtin_amdgcn_update_dpp(
             0, __builtin_bit_cast(int, x), 0x4E, 0xF, 0xF, true));
    x += __builtin_bit_cast(float, __builtin_amdgcn_update_dpp(
             0, __builtin_bit_cast(int, x), 0x124, 0xF, 0xF, true));
    x += __builtin_bit_cast(float, __builtin_amdgcn_update_dpp(
             0, __builtin_bit_cast(int, x), 0x128, 0xF, 0xF, true));
    return x;
}

// ================= weight pre-pack kernels (single fp16) =================
__global__ void prep_w1(const float* __restrict__ W1, const int* __restrict__ G,
                        u16* __restrict__ P) {
    int idx = blockIdx.x * 256 + threadIdx.x;   // 64*64*256 exactly
    int n = idx & 255;
    int k = (idx >> 8) & 63;
    int v = idx >> 14;
    float w = (G[k * 64 + v] > 0) ? W1[((size_t)v * 65 + k) * 256 + n] : 0.0f;
    P[(((size_t)(v * 8 + (k >> 3)) * 256 + n) << 3) + (k & 7)] = f2h(w);
}
__global__ void prep_w2(const float* __restrict__ W2, u16* __restrict__ P) {
    int idx = blockIdx.x * 256 + threadIdx.x;   // 64*256*128 exactly
    int n = idx & 127;
    int k = (idx >> 7) & 255;
    int v = idx >> 15;
    P[(((size_t)(v * 32 + (k >> 3)) * 128 + n) << 3) + (k & 7)] =
        f2h(W2[((size_t)v * 256 + k) * 128 + n]);
}

// ================= persistent fused kernel =================
// One block = 64 batch rows (4 row-sub-tiles of 16), 8 waves, 1 block/CU.
// Weight fragments (global->reg) are shared across the 4 sub-tiles:
// per-CU weight stream is halved vs RT=32x2blocks, and each B-operand
// register feeds 4 independent MFMA chains (ILP to cover latency at
// 2 waves/SIMD).
#define AST   72     // Y-tile stride (u16): 144B = 16 mod 128
#define H1ST  264    // h1 stride (u16): 528B = 16 mod 128

__global__ __launch_bounds__(512, 2)
void sen_fused(const float* __restrict__ U,
               const u16* __restrict__ P1, const u16* __restrict__ P2,
               const float* __restrict__ W1, const float* __restrict__ b1,
               const float* __restrict__ b2, const float* __restrict__ W3,
               const float* __restrict__ b3, float* __restrict__ Y)
{
    __shared__ __attribute__((aligned(16))) u16 Ah[RT * AST];
    __shared__ __attribute__((aligned(16))) u16 Al[RT * AST];
    __shared__ __attribute__((aligned(16))) u16 h1[RT * H1ST];
    __shared__ float yp[8][RT];

    const int tid  = threadIdx.x;
    const int row0 = blockIdx.x * RT;

    // zero Y tile incl. pad (stale LDS bits could be NaN; NaN*0 = NaN in MFMA)
    {
        short8 z = {0,0,0,0,0,0,0,0};
        for (int i = tid; i < (RT * AST) / 8; i += 512) {
            *(short8*)&Ah[i * 8] = z;
            *(short8*)&Al[i * 8] = z;
        }
    }
    __syncthreads();

    const int w  = tid >> 6, l = tid & 63;
    const int lr = l & 15,  lk = l >> 4;
    const int mg = w;   // phase 1: dim group (32 dims, W1 read once/block)
    const int cg = w;   // phase 2: col group (16 cols, W2 read once/block)

    #pragma unroll 1
    for (int v = 0; v < 64; ++v) {
        // ---- per-step parameter loads (latency hides under MFMAs) ----
        f32x4 b1v[2], w64v[2];
        #pragma unroll
        for (int ni = 0; ni < 2; ++ni) {
            const int dim = mg * 32 + ni * 16 + lk * 4;
            b1v[ni]  = *(const f32x4*)(b1 + v * 256 + dim);
            w64v[ni] = *(const f32x4*)(W1 + ((size_t)v * 65 + 64) * 256 + dim);
        }
        float u_c[4];
        #pragma unroll
        for (int nj = 0; nj < 4; ++nj)
            u_c[nj] = U[(size_t)(row0 + nj * 16 + lr) * 64 + v];
        const float b2c = b2[v * 128 + cg * 16 + lr];
        const float w3c = W3[v * 128 + cg * 16 + lr];

        // ======== Phase 1 — Layer 1 (operand-swapped): h1t[dim][brow] ========
        // wave: dims mg*32..+31 (ni=2) x 64 rows (nj=4), K=64.
        // W1 fragment registers shared across the 4 row-sub-tiles.
        f32x4 acc1[4][2];
        #pragma unroll
        for (int nj = 0; nj < 4; ++nj)
            #pragma unroll
            for (int ni = 0; ni < 2; ++ni) acc1[nj][ni] = (f32x4){0.f, 0.f, 0.f, 0.f};

        #pragma unroll
        for (int kt = 0; kt < 2; ++kt) {
            f16x8 Yfh[4], Yfl[4];
            #pragma unroll
            for (int nj = 0; nj < 4; ++nj) {
                const int o = (nj * 16 + lr) * AST + kt * 32 + lk * 8;
                Yfh[nj] = *(const f16x8*)&Ah[o];
                Yfl[nj] = *(const f16x8*)&Al[o];
            }
            #pragma unroll
            for (int ni = 0; ni < 2; ++ni) {
                const f16x8 Wf = *(const f16x8*)&P1[
                    (((size_t)(v * 8 + kt * 4 + lk) * 256) + mg * 32 + ni * 16 + lr) << 3];
                #pragma unroll
                for (int nj = 0; nj < 4; ++nj) {
                    acc1[nj][ni] = __builtin_amdgcn_mfma_f32_16x16x32_f16(Wf, Yfh[nj], acc1[nj][ni], 0, 0, 0);
                    acc1[nj][ni] = __builtin_amdgcn_mfma_f32_16x16x32_f16(Wf, Yfl[nj], acc1[nj][ni], 0, 0, 0);
                }
            }
        }
        // epilogue: + bias + u * W1[64,:] (exact fp32), relu, fp16 pack, store
        #pragma unroll
        for (int nj = 0; nj < 4; ++nj) {
            const int brow = nj * 16 + lr;
            #pragma unroll
            for (int ni = 0; ni < 2; ++ni) {
                float x[4];
                #pragma unroll
                for (int r = 0; r < 4; ++r)
                    x[r] = fmaxf(acc1[nj][ni][r] + b1v[ni][r] + u_c[nj] * w64v[ni][r], 0.0f);
                unsigned long long pk = (unsigned long long)pk2(x[0], x[1])
                                      | ((unsigned long long)pk2(x[2], x[3]) << 32);
                *(unsigned long long*)&h1[brow * H1ST + mg * 32 + ni * 16 + lk * 4] = pk;
            }
        }
        __syncthreads();   // B1: h1 written -> phase 2 may read

        // ======== Phase 2 — Layer 2 (bias via acc init) + in-reg layer 3 ========
        // wave: cols cg*16..+15, rows 64 (mi=4), K=256.
        // W2 fragment registers shared across the 4 row-sub-tiles.
        f32x4 acc2[4];
        #pragma unroll
        for (int mi = 0; mi < 4; ++mi) acc2[mi] = (f32x4){b2c, b2c, b2c, b2c};
        #pragma unroll
        for (int kt = 0; kt < 8; ++kt) {
            const f16x8 Bf = *(const f16x8*)&P2[
                (((size_t)(v * 32 + kt * 4 + lk) * 128) + cg * 16 + lr) << 3];
            #pragma unroll
            for (int mi = 0; mi < 4; ++mi) {
                const f16x8 Hf = *(const f16x8*)&h1[(mi * 16 + lr) * H1ST + kt * 32 + lk * 8];
                acc2[mi] = __builtin_amdgcn_mfma_f32_16x16x32_f16(Hf, Bf, acc2[mi], 0, 0, 0);
            }
        }
        // layer-3 partials: relu * w3, DPP-reduce over the 16 lr lanes (cols)
        #pragma unroll
        for (int mi = 0; mi < 4; ++mi) {
            f32x4 sv;
            #pragma unroll
            for (int r = 0; r < 4; ++r)
                sv[r] = red16(fmaxf(acc2[mi][r], 0.0f) * w3c);
            if (lr == 0)
                *(f32x4*)&yp[cg][mi * 16 + lk * 4] = sv;
        }
        __syncthreads();   // B2: yp visible; all h1 reads done

        // ======== Phase 3 — finalize y column into the Y tile ========
        if (tid < RT) {
            float y = b3[v];
            #pragma unroll
            for (int c = 0; c < 8; ++c) y += yp[c][tid];
            u16 h = f2h(y);
            Ah[tid * AST + v] = h;
            Al[tid * AST + v] = f2h(y - h2f(h));
        }
        __syncthreads();   // B3: Y col v visible; h1 free for next step
    }

    // ---- final coalesced store (hi+lo reconstruct), 8 floats per thread ----
    {
        const int row = tid >> 3, c8 = (tid & 7) * 8;
        const u16* hv = &Ah[row * AST + c8];
        const u16* lv = &Al[row * AST + c8];
        float o[8];
        #pragma unroll
        for (int j = 0; j < 8; ++j) o[j] = h2f(hv[j]) + h2f(lv[j]);
        float4 o0 = {o[0], o[1], o[2], o[3]};
        float4 o1 = {o[4], o[5], o[6], o[7]};
        *(float4*)(Y + (size_t)(row0 + row) * 64 + c8)     = o0;
        *(float4*)(Y + (size_t)(row0 + row) * 64 + c8 + 4) = o1;
    }
}

extern "C" void kernel_launch(void* const* d_in, const int* in_sizes, int n_in,
                              void* d_out, int out_size, void* d_ws, size_t ws_size,
                              hipStream_t stream) {
    // inputs: X, U, causal_graph, W1, b1, W2, b2, W3, b3  (X never feeds the recursion)
    const float* U  = (const float*)d_in[1];
    const int*   G  = (const int*)  d_in[2];
    const float* W1 = (const float*)d_in[3];
    const float* b1 = (const float*)d_in[4];
    const float* W2 = (const float*)d_in[5];
    const float* b2 = (const float*)d_in[6];
    const float* W3 = (const float*)d_in[7];
    const float* b3 = (const float*)d_in[8];
    float* Y = (float*)d_out;

    const size_t S1 = (size_t)64 * 64 * 256;     // u16 elements, packed W1
    u16* P1 = (u16*)d_ws;
    u16* P2 = P1 + S1;

    prep_w1<<<(64 * 64 * 256) / 256, 256, 0, stream>>>(W1, G, P1);
    prep_w2<<<(64 * 256 * 128) / 256, 256, 0, stream>>>(W2, P2);
    sen_fused<<<BATCH / RT, 512, 0, stream>>>(U, P1, P2, W1, b1, b2, W3, b3, Y);
}

// Round 12
// 293.621 us; speedup vs baseline: 1.2488x; 1.0829x over previous
//
#include <hip/hip_runtime.h>

#define BATCH 16384
#define RT    32        // batch rows per block -> 512 blocks -> 2 blocks/CU

typedef unsigned short u16;
typedef __attribute__((ext_vector_type(8))) short short8;
typedef __attribute__((ext_vector_type(8))) _Float16 f16x8;
typedef __attribute__((ext_vector_type(4))) float f32x4;

// ---------- fp16 helpers ----------
__device__ __forceinline__ u16 f2h(float x) {
    union { _Float16 h; u16 u; } c; c.h = (_Float16)x; return c.u;
}
__device__ __forceinline__ float h2f(u16 b) {
    union { u16 u; _Float16 h; } c; c.u = b; return (float)c.h;
}
__device__ __forceinline__ unsigned int pk2(float a, float b) {
    union { __attribute__((ext_vector_type(2))) __fp16 v; unsigned int u; } c;
    c.v = __builtin_amdgcn_cvt_pkrtz(a, b);
    return c.u;
}
// 16-lane sum via DPP (verified R9/R10)
__device__ __forceinline__ float red16(float x) {
    x += __builtin_bit_cast(float, __builtin_amdgcn_update_dpp(
             0, __builtin_bit_cast(int, x), 0xB1, 0xF, 0xF, true));
    x += __builtin_bit_cast(float, __builtin_amdgcn_update_dpp(
             0, __builtin_bit_cast(int, x), 0x4E, 0xF, 0xF, true));
    x += __builtin_bit_cast(float, __builtin_amdgcn_update_dpp(
             0, __builtin_bit_cast(int, x), 0x124, 0xF, 0xF, true));
    x += __builtin_bit_cast(float, __builtin_amdgcn_update_dpp(
             0, __builtin_bit_cast(int, x), 0x128, 0xF, 0xF, true));
    return x;
}
// insert element jv (runtime 0..7) into an f16x8 with static indices only
__device__ __forceinline__ void ins(f16x8& f, int jv, u16 val) {
    _Float16 hv = __builtin_bit_cast(_Float16, val);
    #pragma unroll
    for (int j = 0; j < 8; ++j) if (j == jv) f[j] = hv;
}

// ================= weight pre-pack kernels (single fp16) =================
__global__ void prep_w1(const float* __restrict__ W1, const int* __restrict__ G,
                        u16* __restrict__ P) {
    int idx = blockIdx.x * 256 + threadIdx.x;   // 64*64*256 exactly
    int n = idx & 255;
    int k = (idx >> 8) & 63;
    int v = idx >> 14;
    float w = (G[k * 64 + v] > 0) ? W1[((size_t)v * 65 + k) * 256 + n] : 0.0f;
    P[(((size_t)(v * 8 + (k >> 3)) * 256 + n) << 3) + (k & 7)] = f2h(w);
}
__global__ void prep_w2(const float* __restrict__ W2, u16* __restrict__ P) {
    int idx = blockIdx.x * 256 + threadIdx.x;   // 64*256*128 exactly
    int n = idx & 127;
    int k = (idx >> 7) & 255;
    int v = idx >> 15;
    P[(((size_t)(v * 32 + (k >> 3)) * 128 + n) << 3) + (k & 7)] =
        f2h(W2[((size_t)v * 256 + k) * 128 + n]);
}

// ================= persistent fused kernel =================
// Y lives ONLY in registers as MFMA B-fragments (hi/lo fp16, 8 frags):
// each step patches one element (column v) per holding lane. No Y LDS
// reads, no finalize barrier, no serial finalize. 2 barriers/step.
#define H1ST  264    // h1 stride (u16): 528B = 16 mod 128
#define YOST  68     // Yout stride (f32)

__global__ __launch_bounds__(512, 4)
void sen_fused(const float* __restrict__ U,
               const u16* __restrict__ P1, const u16* __restrict__ P2,
               const float* __restrict__ W1, const float* __restrict__ b1,
               const float* __restrict__ b2, const float* __restrict__ W3,
               const float* __restrict__ b3, float* __restrict__ Y)
{
    __shared__ __attribute__((aligned(16))) u16 h1[RT * H1ST];
    __shared__ __attribute__((aligned(16))) float yp[RT][12];  // [row][cg 0..7 +pad]
    __shared__ __attribute__((aligned(16))) float Yout[RT * YOST];

    const int tid  = threadIdx.x;
    const int row0 = blockIdx.x * RT;

    const int w  = tid >> 6, l = tid & 63;
    const int lr = l & 15,  lk = l >> 4;
    const int mg = w;   // phase 1: dim group (32 dims, W1 read once/block)
    const int cg = w;   // phase 2: col group (16 cols, W2 read once/block)

    // register-resident Y fragments: lane holds Y[row nj*16+lr][cols kt*32+lk*8 ..+8]
    f16x8 Yh[2][2], Yl[2][2];
    {
        f16x8 z;
        #pragma unroll
        for (int j = 0; j < 8; ++j) z[j] = (_Float16)0.0f;
        #pragma unroll
        for (int kt = 0; kt < 2; ++kt)
            #pragma unroll
            for (int nj = 0; nj < 2; ++nj) { Yh[kt][nj] = z; Yl[kt][nj] = z; }
    }

    #pragma unroll 1
    for (int v = 0; v < 64; ++v) {
        // ---- per-step parameter loads ----
        f32x4 b1v[2], w64v[2];
        #pragma unroll
        for (int ni = 0; ni < 2; ++ni) {
            const int dim = mg * 32 + ni * 16 + lk * 4;
            b1v[ni]  = *(const f32x4*)(b1 + v * 256 + dim);
            w64v[ni] = *(const f32x4*)(W1 + ((size_t)v * 65 + 64) * 256 + dim);
        }
        float u_c[2];
        #pragma unroll
        for (int nj = 0; nj < 2; ++nj)
            u_c[nj] = U[(size_t)(row0 + nj * 16 + lr) * 64 + v];
        const float b2c = b2[v * 128 + cg * 16 + lr];
        const float w3c = W3[v * 128 + cg * 16 + lr];
        const float b3v = b3[v];

        // ======== Phase 1 — Layer 1 (operand-swapped), Y from registers ========
        f32x4 acc1[2][2];
        #pragma unroll
        for (int nj = 0; nj < 2; ++nj)
            #pragma unroll
            for (int ni = 0; ni < 2; ++ni) acc1[nj][ni] = (f32x4){0.f, 0.f, 0.f, 0.f};

        #pragma unroll
        for (int kt = 0; kt < 2; ++kt)
            #pragma unroll
            for (int ni = 0; ni < 2; ++ni) {
                const f16x8 Wf = *(const f16x8*)&P1[
                    (((size_t)(v * 8 + kt * 4 + lk) * 256) + mg * 32 + ni * 16 + lr) << 3];
                #pragma unroll
                for (int nj = 0; nj < 2; ++nj) {
                    acc1[nj][ni] = __builtin_amdgcn_mfma_f32_16x16x32_f16(Wf, Yh[kt][nj], acc1[nj][ni], 0, 0, 0);
                    acc1[nj][ni] = __builtin_amdgcn_mfma_f32_16x16x32_f16(Wf, Yl[kt][nj], acc1[nj][ni], 0, 0, 0);
                }
            }
        // epilogue: + bias + u * W1[64,:] (exact fp32), relu, fp16 pack, store
        #pragma unroll
        for (int nj = 0; nj < 2; ++nj) {
            const int brow = nj * 16 + lr;
            #pragma unroll
            for (int ni = 0; ni < 2; ++ni) {
                float x[4];
                #pragma unroll
                for (int r = 0; r < 4; ++r)
                    x[r] = fmaxf(acc1[nj][ni][r] + b1v[ni][r] + u_c[nj] * w64v[ni][r], 0.0f);
                unsigned long long pk = (unsigned long long)pk2(x[0], x[1])
                                      | ((unsigned long long)pk2(x[2], x[3]) << 32);
                *(unsigned long long*)&h1[brow * H1ST + mg * 32 + ni * 16 + lk * 4] = pk;
            }
        }
        __syncthreads();   // B1: h1 written -> phase 2 may read

        // ======== Phase 2 — Layer 2 (bias via acc init) + in-reg layer 3 ========
        f32x4 acc2[2];
        acc2[0] = (f32x4){b2c, b2c, b2c, b2c};
        acc2[1] = acc2[0];
        #pragma unroll
        for (int kt = 0; kt < 8; ++kt) {
            const f16x8 Bf = *(const f16x8*)&P2[
                (((size_t)(v * 32 + kt * 4 + lk) * 128) + cg * 16 + lr) << 3];
            #pragma unroll
            for (int mi = 0; mi < 2; ++mi) {
                const f16x8 Hf = *(const f16x8*)&h1[(mi * 16 + lr) * H1ST + kt * 32 + lk * 8];
                acc2[mi] = __builtin_amdgcn_mfma_f32_16x16x32_f16(Hf, Bf, acc2[mi], 0, 0, 0);
            }
        }
        // layer-3 partials: relu * w3, DPP-reduce over 16 col-lanes; lane lr==0
        // writes yp[row][cg]
        #pragma unroll
        for (int mi = 0; mi < 2; ++mi) {
            float s0 = red16(fmaxf(acc2[mi][0], 0.0f) * w3c);
            float s1 = red16(fmaxf(acc2[mi][1], 0.0f) * w3c);
            float s2 = red16(fmaxf(acc2[mi][2], 0.0f) * w3c);
            float s3 = red16(fmaxf(acc2[mi][3], 0.0f) * w3c);
            if (lr == 0) {
                const int row = mi * 16 + lk * 4;
                yp[row + 0][cg] = s0;
                yp[row + 1][cg] = s1;
                yp[row + 2][cg] = s2;
                yp[row + 3][cg] = s3;
            }
        }
        __syncthreads();   // B2: yp complete

        // ======== per-lane y compute + register patch (no barrier needed) ========
        float y[2];
        #pragma unroll
        for (int nj = 0; nj < 2; ++nj) {
            const int row = nj * 16 + lr;
            const f32x4 a = *(const f32x4*)&yp[row][0];
            const f32x4 b = *(const f32x4*)&yp[row][4];
            // fixed left-to-right order -> identical value in every lane/wave
            y[nj] = b3v + a[0] + a[1] + a[2] + a[3] + b[0] + b[1] + b[2] + b[3];
        }
        if (w == 0 && lk == 0) {
            Yout[lr * YOST + v]        = y[0];
            Yout[(16 + lr) * YOST + v] = y[1];
        }
        const u16 yh0 = f2h(y[0]);
        const u16 yl0 = f2h(y[0] - h2f(yh0));
        const u16 yh1 = f2h(y[1]);
        const u16 yl1 = f2h(y[1] - h2f(yh1));
        const int jv = v & 7;
        if (((v >> 3) & 3) == lk) {
            if (v < 32) {
                ins(Yh[0][0], jv, yh0); ins(Yl[0][0], jv, yl0);
                ins(Yh[0][1], jv, yh1); ins(Yl[0][1], jv, yl1);
            } else {
                ins(Yh[1][0], jv, yh0); ins(Yl[1][0], jv, yl0);
                ins(Yh[1][1], jv, yh1); ins(Yl[1][1], jv, yl1);
            }
        }
        // h1/yp reuse fenced by next step's B1/B2; Yout read only after loop.
    }
    __syncthreads();   // Yout complete

    // ---- final coalesced store (exact f32), 1 float4 per thread ----
    {
        const int row = tid >> 4, c4 = (tid & 15) * 4;
        *(float4*)(Y + (size_t)(row0 + row) * 64 + c4) = *(float4*)&Yout[row * YOST + c4];
    }
}

extern "C" void kernel_launch(void* const* d_in, const int* in_sizes, int n_in,
                              void* d_out, int out_size, void* d_ws, size_t ws_size,
                              hipStream_t stream) {
    // inputs: X, U, causal_graph, W1, b1, W2, b2, W3, b3  (X never feeds the recursion)
    const float* U  = (const float*)d_in[1];
    const int*   G  = (const int*)  d_in[2];
    const float* W1 = (const float*)d_in[3];
    const float* b1 = (const float*)d_in[4];
    const float* W2 = (const float*)d_in[5];
    const float* b2 = (const float*)d_in[6];
    const float* W3 = (const float*)d_in[7];
    const float* b3 = (const float*)d_in[8];
    float* Y = (float*)d_out;

    const size_t S1 = (size_t)64 * 64 * 256;     // u16 elements, packed W1
    u16* P1 = (u16*)d_ws;
    u16* P2 = P1 + S1;

    prep_w1<<<(64 * 64 * 256) / 256, 256, 0, stream>>>(W1, G, P1);
    prep_w2<<<(64 * 256 * 128) / 256, 256, 0, stream>>>(W2, P2);
    sen_fused<<<BATCH / RT, 512, 0, stream>>>(U, P1, P2, W1, b1, b2, W3, b3, Y);
}